// Round 1
// baseline (386.386 us; speedup 1.0000x reference)
//
#include <hip/hip_runtime.h>
#include <stdint.h>

typedef __attribute__((ext_vector_type(8))) short bf16x8;
typedef __attribute__((ext_vector_type(4))) float f32x4;

#define CH_STRIDE 65536  // T*W*H = 16*64*64

__device__ __forceinline__ uint16_t f2bf(float f) {
  uint32_t u = __builtin_bit_cast(uint32_t, f);
  u = (u + 0x7FFFu + ((u >> 16) & 1u)) >> 16;
  return (uint16_t)u;
}

// XOR swizzle: spread stride-128B column accesses across 8 16B slots.
__device__ __forceinline__ uint32_t swz(uint32_t b) {
  return b ^ (((b >> 7) & 7u) << 4);
}

// Stage x tile for one (b,t) slice: rows w0-1..w0+4 (6), cols -1..64 (66),
// all 64 channels, as bf16 in LDS layout [row][col][ch] (ch contiguous),
// zero-padded at borders, swizzled.
__device__ __forceinline__ void stage_x(uint8_t* lds, const float* xs, int w0, int tid) {
  for (int i = tid; i < 6 * 66 * 16; i += 256) {
    int qd  = i / 396;          // channel quad 0..15
    int rem = i - qd * 396;
    int r   = rem / 66;         // tile row 0..5
    int c   = rem - r * 66;     // tile col 0..65
    int w = w0 - 1 + r;
    int h = c - 1;
    uint64_t val = 0;
    if ((unsigned)w < 64u && (unsigned)h < 64u) {
      const float* p = xs + (size_t)qd * 4 * CH_STRIDE + w * 64 + h;
      uint32_t lo = (uint32_t)f2bf(p[0]) | ((uint32_t)f2bf(p[CH_STRIDE]) << 16);
      uint32_t hi = (uint32_t)f2bf(p[2 * CH_STRIDE]) | ((uint32_t)f2bf(p[3 * CH_STRIDE]) << 16);
      val = (uint64_t)lo | ((uint64_t)hi << 32);
    }
    uint32_t byte = (uint32_t)(r * 66 + c) * 128u + (uint32_t)qd * 8u;
    *(uint64_t*)(lds + swz(byte)) = val;
  }
}

// B-fragment: X[k, n] for 16x16x32 mfma. lane&15 -> position (col), lane>>4 -> k-block.
__device__ __forceinline__ bf16x8 read_b(const uint8_t* lds, int row, int col, int kbase, int l) {
  uint32_t byte = (uint32_t)(row * 66 + col) * 128u + (uint32_t)(kbase + ((l >> 4) * 8)) * 2u;
  return *(const bf16x8*)(lds + swz(byte));
}

#define MFMA(a, b, c) __builtin_amdgcn_mfma_f32_16x16x32_bf16(a, b, c, 0, 0, 0)

// ---------------------------------------------------------------------------
// Pre-kernel: weights fp32 [o][i][tap] -> bf16 [conv][m][K], K = tap*64 + ch
// ---------------------------------------------------------------------------
__global__ void prep_weights(const float* __restrict__ wq, const float* __restrict__ wk,
                             const float* __restrict__ wv, uint16_t* __restrict__ wout) {
  int i = blockIdx.x * 256 + threadIdx.x;
  if (i >= 3 * 64 * 576) return;
  int conv = i / 36864;
  int rem  = i - conv * 36864;
  int m    = rem / 576;
  int kk   = rem - m * 576;
  int tap  = kk >> 6;
  int ch   = kk & 63;
  const float* src = (conv == 0) ? wq : (conv == 1) ? wk : wv;
  wout[i] = f2bf(src[(m * 64 + ch) * 9 + tap]);
}

// ---------------------------------------------------------------------------
// Kernel 1: k,v conv (M=128 fused) for a 4-row x 64-col tile, then
// s[b,c,t] += sum_pos (k+bk)*(v+bv) via shfl-reduce + atomicAdd.
// ---------------------------------------------------------------------------
__global__ __launch_bounds__(256, 2) void kv_s_kernel(
    const float* __restrict__ x, const uint16_t* __restrict__ wkv,
    const float* __restrict__ bk, const float* __restrict__ bv,
    float* __restrict__ s_out) {
  __shared__ uint8_t lds[6 * 66 * 128];
  int tid = threadIdx.x;
  int l   = tid & 63;
  int wid = tid >> 6;
  int bid = blockIdx.x;
  int rg    = bid & 15;
  int slice = bid >> 4;
  int b = slice >> 4, t = slice & 15;
  int w0 = rg * 4;
  const float* xs = x + ((size_t)b * 64 * 16 + t) * 4096;
  stage_x(lds, xs, w0, tid);
  __syncthreads();

  int mg = wid >> 1;  // channel-half group (ch 0..31 or 32..63, for both k and v)
  int ng = wid & 1;   // n-tile half
  int lm = l & 15, lk = l >> 4;

  f32x4 acc[4][8];
  #pragma unroll
  for (int mi = 0; mi < 4; ++mi)
    #pragma unroll
    for (int nj = 0; nj < 8; ++nj) acc[mi][nj] = (f32x4){0.f, 0.f, 0.f, 0.f};

  const uint16_t* wr0 = wkv + (size_t)(mg * 32 + lm) * 576;       // k rows
  const uint16_t* wr2 = wkv + (size_t)(64 + mg * 32 + lm) * 576;  // v rows

  #pragma unroll
  for (int tap = 0; tap < 9; ++tap) {
    int dy = tap / 3, dx = tap % 3;
    #pragma unroll
    for (int kh = 0; kh < 2; ++kh) {
      int K = tap * 64 + kh * 32 + lk * 8;
      bf16x8 a0 = *(const bf16x8*)(wr0 + K);
      bf16x8 a1 = *(const bf16x8*)(wr0 + 16 * 576 + K);
      bf16x8 a2 = *(const bf16x8*)(wr2 + K);
      bf16x8 a3 = *(const bf16x8*)(wr2 + 16 * 576 + K);
      #pragma unroll
      for (int nj = 0; nj < 8; ++nj) {
        int nt  = ng * 8 + nj;
        int row = (nt >> 2) + dy;
        int col = (nt & 3) * 16 + lm + dx;
        bf16x8 bb = read_b(lds, row, col, kh * 32, l);
        acc[0][nj] = MFMA(a0, bb, acc[0][nj]);
        acc[1][nj] = MFMA(a1, bb, acc[1][nj]);
        acc[2][nj] = MFMA(a2, bb, acc[2][nj]);
        acc[3][nj] = MFMA(a3, bb, acc[3][nj]);
      }
    }
  }

  // epilogue: per-lane partial of sum_pos (k+bk)(v+bv), c = mg*32 + mi*16 + lk*4 + r
  int c0 = mg * 32 + lk * 4;
  f32x4 bk0 = *(const f32x4*)(bk + c0);
  f32x4 bk1 = *(const f32x4*)(bk + c0 + 16);
  f32x4 bv0 = *(const f32x4*)(bv + c0);
  f32x4 bv1 = *(const f32x4*)(bv + c0 + 16);

  float sum0[4], sum1[4];
  #pragma unroll
  for (int r = 0; r < 4; ++r) { sum0[r] = 0.f; sum1[r] = 0.f; }
  #pragma unroll
  for (int nj = 0; nj < 8; ++nj) {
    #pragma unroll
    for (int r = 0; r < 4; ++r) {
      sum0[r] += (acc[0][nj][r] + bk0[r]) * (acc[2][nj][r] + bv0[r]);
      sum1[r] += (acc[1][nj][r] + bk1[r]) * (acc[3][nj][r] + bv1[r]);
    }
  }
  // reduce over the 16 lanes (l&15) that hold different positions of same c
  #pragma unroll
  for (int r = 0; r < 4; ++r) {
    #pragma unroll
    for (int m = 1; m < 16; m <<= 1) {
      sum0[r] += __shfl_xor(sum0[r], m, 64);
      sum1[r] += __shfl_xor(sum1[r], m, 64);
    }
  }
  if ((l & 15) == 0) {
    float* sb = s_out + (b * 16 + t) * 64;
    #pragma unroll
    for (int r = 0; r < 4; ++r) {
      atomicAdd(sb + c0 + r, sum0[r]);
      atomicAdd(sb + c0 + 16 + r, sum1[r]);
    }
  }
}

// ---------------------------------------------------------------------------
// Kernel 2: q conv (M=64) + out = gamma*q*s + x
// ---------------------------------------------------------------------------
__global__ __launch_bounds__(256, 2) void q_out_kernel(
    const float* __restrict__ x, const uint16_t* __restrict__ wq,
    const float* __restrict__ bq, const float* __restrict__ s_in,
    const float* __restrict__ gamma, float* __restrict__ out) {
  __shared__ uint8_t lds[6 * 66 * 128];
  int tid = threadIdx.x;
  int l   = tid & 63;
  int wid = tid >> 6;
  int bid = blockIdx.x;
  int rg    = bid & 15;
  int slice = bid >> 4;
  int b = slice >> 4, t = slice & 15;
  int w0 = rg * 4;
  const float* xs = x + ((size_t)b * 64 * 16 + t) * 4096;
  stage_x(lds, xs, w0, tid);
  __syncthreads();

  int lm = l & 15, lk = l >> 4;
  f32x4 acc[4][4];
  #pragma unroll
  for (int mi = 0; mi < 4; ++mi)
    #pragma unroll
    for (int nj = 0; nj < 4; ++nj) acc[mi][nj] = (f32x4){0.f, 0.f, 0.f, 0.f};

  const uint16_t* wr = wq + (size_t)lm * 576;

  #pragma unroll
  for (int tap = 0; tap < 9; ++tap) {
    int dy = tap / 3, dx = tap % 3;
    #pragma unroll
    for (int kh = 0; kh < 2; ++kh) {
      int K = tap * 64 + kh * 32 + lk * 8;
      bf16x8 a0 = *(const bf16x8*)(wr + K);
      bf16x8 a1 = *(const bf16x8*)(wr + 16 * 576 + K);
      bf16x8 a2 = *(const bf16x8*)(wr + 32 * 576 + K);
      bf16x8 a3 = *(const bf16x8*)(wr + 48 * 576 + K);
      #pragma unroll
      for (int nj = 0; nj < 4; ++nj) {
        int nt  = wid * 4 + nj;
        int row = (nt >> 2) + dy;            // = wid + dy
        int col = (nt & 3) * 16 + lm + dx;   // = nj*16 + lm + dx
        bf16x8 bb = read_b(lds, row, col, kh * 32, l);
        acc[0][nj] = MFMA(a0, bb, acc[0][nj]);
        acc[1][nj] = MFMA(a1, bb, acc[1][nj]);
        acc[2][nj] = MFMA(a2, bb, acc[2][nj]);
        acc[3][nj] = MFMA(a3, bb, acc[3][nj]);
      }
    }
  }

  float g = gamma[0];
  const float* sb = s_in + (b * 16 + t) * 64;
  #pragma unroll
  for (int mi = 0; mi < 4; ++mi) {
    f32x4 bq4 = *(const f32x4*)(bq + mi * 16 + lk * 4);
    f32x4 s4  = *(const f32x4*)(sb + mi * 16 + lk * 4);
    #pragma unroll
    for (int nj = 0; nj < 4; ++nj) {
      int w = w0 + wid;
      int h = nj * 16 + lm;
      #pragma unroll
      for (int r = 0; r < 4; ++r) {
        int c = mi * 16 + lk * 4 + r;
        size_t idx = ((size_t)(b * 64 + c) * 16 + t) * 4096 + (size_t)w * 64 + h;
        out[idx] = g * (acc[mi][nj][r] + bq4[r]) * s4[r] + x[idx];
      }
    }
  }
}

extern "C" void kernel_launch(void* const* d_in, const int* in_sizes, int n_in,
                              void* d_out, int out_size, void* d_ws, size_t ws_size,
                              hipStream_t stream) {
  const float* x   = (const float*)d_in[0];
  const float* wq  = (const float*)d_in[1];
  const float* wk  = (const float*)d_in[2];
  const float* wv  = (const float*)d_in[3];
  const float* bq  = (const float*)d_in[4];
  const float* bk  = (const float*)d_in[5];
  const float* bv  = (const float*)d_in[6];
  const float* gam = (const float*)d_in[7];

  uint16_t* wbf = (uint16_t*)d_ws;                       // 3 * 64*576 bf16 = 221184 B
  float* sbuf   = (float*)((uint8_t*)d_ws + 3 * 36864 * 2);  // 8192 floats

  hipMemsetAsync(sbuf, 0, 8 * 16 * 64 * sizeof(float), stream);
  prep_weights<<<(3 * 64 * 576 + 255) / 256, 256, 0, stream>>>(wq, wk, wv, wbf);
  kv_s_kernel<<<2048, 256, 0, stream>>>(x, wbf + 36864, bk, bv, sbuf);
  q_out_kernel<<<2048, 256, 0, stream>>>(x, wbf, bq, sbuf, gam, (float*)d_out);
}

// Round 4
// 381.084 us; speedup vs baseline: 1.0139x; 1.0139x over previous
//
#include <hip/hip_runtime.h>
#include <stdint.h>

typedef __attribute__((ext_vector_type(8))) short bf16x8;
typedef __attribute__((ext_vector_type(4))) float f32x4;

#define CH_STRIDE 65536  // T*W*H = 16*64*64

__device__ __forceinline__ uint16_t f2bf(float f) {
  uint32_t u = __builtin_bit_cast(uint32_t, f);
  u = (u + 0x7FFFu + ((u >> 16) & 1u)) >> 16;
  return (uint16_t)u;
}

__device__ __forceinline__ float bf2f(uint32_t b) {
  return __builtin_bit_cast(float, b << 16);
}

// XOR swizzle: spread stride-128B column accesses across 8 16B slots.
__device__ __forceinline__ uint32_t swz(uint32_t b) {
  return b ^ (((b >> 7) & 7u) << 4);
}

// Stage x tile for one (b,t) slice: rows w0-1..w0+4 (6), cols -1..64 (66),
// all 64 channels, bf16, LDS layout [row][col][ch], zero-padded, swizzled.
// 512-thread blocks.
__device__ __forceinline__ void stage_x(uint8_t* lds, const float* xs, int w0, int tid) {
  for (int i = tid; i < 6 * 66 * 16; i += 512) {
    int qd  = i / 396;          // channel quad 0..15
    int rem = i - qd * 396;
    int r   = rem / 66;         // tile row 0..5
    int c   = rem - r * 66;     // tile col 0..65
    int w = w0 - 1 + r;
    int h = c - 1;
    uint64_t val = 0;
    if ((unsigned)w < 64u && (unsigned)h < 64u) {
      const float* p = xs + (size_t)qd * 4 * CH_STRIDE + w * 64 + h;
      uint32_t lo = (uint32_t)f2bf(p[0]) | ((uint32_t)f2bf(p[CH_STRIDE]) << 16);
      uint32_t hi = (uint32_t)f2bf(p[2 * CH_STRIDE]) | ((uint32_t)f2bf(p[3 * CH_STRIDE]) << 16);
      val = (uint64_t)lo | ((uint64_t)hi << 32);
    }
    uint32_t byte = (uint32_t)(r * 66 + c) * 128u + (uint32_t)qd * 8u;
    *(uint64_t*)(lds + swz(byte)) = val;
  }
}

// B-fragment: X[k, n] for 16x16x32 mfma. lane&15 -> position, lane>>4 -> k-block.
__device__ __forceinline__ bf16x8 read_b(const uint8_t* lds, int row, int col, int kbase, int l) {
  uint32_t byte = (uint32_t)(row * 66 + col) * 128u + (uint32_t)(kbase + ((l >> 4) * 8)) * 2u;
  return *(const bf16x8*)(lds + swz(byte));
}

#define MFMA(a, b, c) __builtin_amdgcn_mfma_f32_16x16x32_bf16(a, b, c, 0, 0, 0)

// ---------------------------------------------------------------------------
// Pre-kernel: weights fp32 [o][i][tap] -> bf16 [conv][m][K], K = tap*64 + ch
// ---------------------------------------------------------------------------
__global__ void prep_weights(const float* __restrict__ wq, const float* __restrict__ wk,
                             const float* __restrict__ wv, uint16_t* __restrict__ wout) {
  int i = blockIdx.x * 256 + threadIdx.x;
  if (i >= 3 * 64 * 576) return;
  int conv = i / 36864;
  int rem  = i - conv * 36864;
  int m    = rem / 576;
  int kk   = rem - m * 576;
  int tap  = kk >> 6;
  int ch   = kk & 63;
  const float* src = (conv == 0) ? wq : (conv == 1) ? wk : wv;
  wout[i] = f2bf(src[(m * 64 + ch) * 9 + tap]);
}

// ---------------------------------------------------------------------------
// Kernel 1: k,v conv (M=128 fused) on a 4-row x 64-col tile; 8 waves.
// Wave: mg = wid>>2 (channel half), ng = wid&3 (output row).
// acc[0..1] = k-tiles (ch mg*32+0..15, +16..31), acc[2..3] = v-tiles.
// Epilogue: s[b,c,t] += sum_pos (k+bk)*(v+bv) via shfl-reduce + atomicAdd.
// ---------------------------------------------------------------------------
__global__ __launch_bounds__(512, 4) void kv_s_kernel(
    const float* __restrict__ x, const uint16_t* __restrict__ wkv,
    const float* __restrict__ bk, const float* __restrict__ bv,
    float* __restrict__ s_out) {
  __shared__ uint8_t lds[6 * 66 * 128];
  int tid = threadIdx.x;
  int l   = tid & 63;
  int wid = tid >> 6;
  int bid = blockIdx.x;
  int rg    = bid & 15;
  int slice = bid >> 4;
  int b = slice >> 4, t = slice & 15;
  int w0 = rg * 4;
  const float* xs = x + ((size_t)b * 64 * 16 + t) * 4096;
  stage_x(lds, xs, w0, tid);
  __syncthreads();

  int mg = wid >> 2;  // channel half (0: ch 0..31, 1: ch 32..63) for both k and v
  int ng = wid & 3;   // output row within tile
  int lm = l & 15, lk = l >> 4;

  f32x4 acc[4][4];
  #pragma unroll
  for (int mi = 0; mi < 4; ++mi)
    #pragma unroll
    for (int nj = 0; nj < 4; ++nj) acc[mi][nj] = (f32x4){0.f, 0.f, 0.f, 0.f};

  const uint16_t* wr0 = wkv + (size_t)(mg * 32 + lm) * 576;       // k rows
  const uint16_t* wr2 = wkv + (size_t)(64 + mg * 32 + lm) * 576;  // v rows

  #pragma unroll
  for (int tap = 0; tap < 9; ++tap) {
    int dy = tap / 3, dx = tap % 3;
    #pragma unroll
    for (int kh = 0; kh < 2; ++kh) {
      int K = tap * 64 + kh * 32 + lk * 8;
      bf16x8 a0 = *(const bf16x8*)(wr0 + K);
      bf16x8 a1 = *(const bf16x8*)(wr0 + 16 * 576 + K);
      bf16x8 a2 = *(const bf16x8*)(wr2 + K);
      bf16x8 a3 = *(const bf16x8*)(wr2 + 16 * 576 + K);
      #pragma unroll
      for (int nj = 0; nj < 4; ++nj) {
        int row = ng + dy;
        int col = nj * 16 + lm + dx;
        bf16x8 bb = read_b(lds, row, col, kh * 32, l);
        acc[0][nj] = MFMA(a0, bb, acc[0][nj]);
        acc[1][nj] = MFMA(a1, bb, acc[1][nj]);
        acc[2][nj] = MFMA(a2, bb, acc[2][nj]);
        acc[3][nj] = MFMA(a3, bb, acc[3][nj]);
      }
    }
  }

  // epilogue: per-lane partial of sum_pos (k+bk)(v+bv), c = mg*32 + {0,16} + lk*4 + r
  int c0 = mg * 32 + lk * 4;
  f32x4 bk0 = *(const f32x4*)(bk + c0);
  f32x4 bk1 = *(const f32x4*)(bk + c0 + 16);
  f32x4 bv0 = *(const f32x4*)(bv + c0);
  f32x4 bv1 = *(const f32x4*)(bv + c0 + 16);

  float sum0[4], sum1[4];
  #pragma unroll
  for (int r = 0; r < 4; ++r) { sum0[r] = 0.f; sum1[r] = 0.f; }
  #pragma unroll
  for (int nj = 0; nj < 4; ++nj) {
    #pragma unroll
    for (int r = 0; r < 4; ++r) {
      sum0[r] += (acc[0][nj][r] + bk0[r]) * (acc[2][nj][r] + bv0[r]);
      sum1[r] += (acc[1][nj][r] + bk1[r]) * (acc[3][nj][r] + bv1[r]);
    }
  }
  // reduce over the 16 lanes (lm) that hold different positions of same c
  #pragma unroll
  for (int r = 0; r < 4; ++r) {
    #pragma unroll
    for (int m = 1; m < 16; m <<= 1) {
      sum0[r] += __shfl_xor(sum0[r], m, 64);
      sum1[r] += __shfl_xor(sum1[r], m, 64);
    }
  }
  if ((l & 15) == 0) {
    float* sb = s_out + (b * 16 + t) * 64;
    #pragma unroll
    for (int r = 0; r < 4; ++r) {
      atomicAdd(sb + c0 + r, sum0[r]);
      atomicAdd(sb + c0 + 16 + r, sum1[r]);
    }
  }
}

// ---------------------------------------------------------------------------
// Kernel 2: q conv (M=64) + out = gamma*q*s + x; 8 waves.
// Wave: nt = wid*2 + nj (nj=0..1); all 4 m-tiles per wave. acc[4][2].
// Residual x read back from the staged bf16 LDS tile (saves 268 MB HBM).
// ---------------------------------------------------------------------------
__global__ __launch_bounds__(512, 4) void q_out_kernel(
    const float* __restrict__ x, const uint16_t* __restrict__ wq,
    const float* __restrict__ bq, const float* __restrict__ s_in,
    const float* __restrict__ gamma, float* __restrict__ out) {
  __shared__ uint8_t lds[6 * 66 * 128];
  int tid = threadIdx.x;
  int l   = tid & 63;
  int wid = tid >> 6;
  int bid = blockIdx.x;
  int rg    = bid & 15;
  int slice = bid >> 4;
  int b = slice >> 4, t = slice & 15;
  int w0 = rg * 4;
  const float* xs = x + ((size_t)b * 64 * 16 + t) * 4096;
  stage_x(lds, xs, w0, tid);
  __syncthreads();

  int lm = l & 15, lk = l >> 4;
  f32x4 acc[4][2];
  #pragma unroll
  for (int mi = 0; mi < 4; ++mi)
    #pragma unroll
    for (int nj = 0; nj < 2; ++nj) acc[mi][nj] = (f32x4){0.f, 0.f, 0.f, 0.f};

  const uint16_t* wr = wq + (size_t)lm * 576;

  #pragma unroll
  for (int tap = 0; tap < 9; ++tap) {
    int dy = tap / 3, dx = tap % 3;
    #pragma unroll
    for (int kh = 0; kh < 2; ++kh) {
      int K = tap * 64 + kh * 32 + lk * 8;
      bf16x8 a0 = *(const bf16x8*)(wr + K);
      bf16x8 a1 = *(const bf16x8*)(wr + 16 * 576 + K);
      bf16x8 a2 = *(const bf16x8*)(wr + 32 * 576 + K);
      bf16x8 a3 = *(const bf16x8*)(wr + 48 * 576 + K);
      #pragma unroll
      for (int nj = 0; nj < 2; ++nj) {
        int nt  = wid * 2 + nj;
        int row = (nt >> 2) + dy;
        int col = (nt & 3) * 16 + lm + dx;
        bf16x8 bb = read_b(lds, row, col, kh * 32, l);
        acc[0][nj] = MFMA(a0, bb, acc[0][nj]);
        acc[1][nj] = MFMA(a1, bb, acc[1][nj]);
        acc[2][nj] = MFMA(a2, bb, acc[2][nj]);
        acc[3][nj] = MFMA(a3, bb, acc[3][nj]);
      }
    }
  }

  float g = gamma[0];
  const float* sb = s_in + (b * 16 + t) * 64;
  #pragma unroll
  for (int nj = 0; nj < 2; ++nj) {
    int nt = wid * 2 + nj;
    int w  = w0 + (nt >> 2);
    int h  = (nt & 3) * 16 + lm;
    uint32_t xbyte = (uint32_t)(((nt >> 2) + 1) * 66 + (h + 1)) * 128u;
    #pragma unroll
    for (int mi = 0; mi < 4; ++mi) {
      int c0 = mi * 16 + lk * 4;
      f32x4 bq4 = *(const f32x4*)(bq + c0);
      f32x4 s4  = *(const f32x4*)(sb + c0);
      uint64_t xb = *(const uint64_t*)(lds + swz(xbyte + (uint32_t)c0 * 2u));
      #pragma unroll
      for (int r = 0; r < 4; ++r) {
        int c = c0 + r;
        float xv = bf2f((uint32_t)((xb >> (16 * r)) & 0xFFFFu));
        size_t idx = ((size_t)(b * 64 + c) * 16 + t) * 4096 + (size_t)w * 64 + h;
        out[idx] = g * (acc[mi][nj][r] + bq4[r]) * s4[r] + xv;
      }
    }
  }
}

extern "C" void kernel_launch(void* const* d_in, const int* in_sizes, int n_in,
                              void* d_out, int out_size, void* d_ws, size_t ws_size,
                              hipStream_t stream) {
  const float* x   = (const float*)d_in[0];
  const float* wq  = (const float*)d_in[1];
  const float* wk  = (const float*)d_in[2];
  const float* wv  = (const float*)d_in[3];
  const float* bq  = (const float*)d_in[4];
  const float* bk  = (const float*)d_in[5];
  const float* bv  = (const float*)d_in[6];
  const float* gam = (const float*)d_in[7];

  uint16_t* wbf = (uint16_t*)d_ws;                           // 3 * 64*576 bf16
  float* sbuf   = (float*)((uint8_t*)d_ws + 3 * 36864 * 2);  // 8192 floats

  hipMemsetAsync(sbuf, 0, 8 * 16 * 64 * sizeof(float), stream);
  prep_weights<<<(3 * 64 * 576 + 255) / 256, 256, 0, stream>>>(wq, wk, wv, wbf);
  kv_s_kernel<<<2048, 512, 0, stream>>>(x, wbf + 36864, bk, bv, sbuf);
  q_out_kernel<<<2048, 512, 0, stream>>>(x, wbf, bq, sbuf, gam, (float*)d_out);
}

// Round 5
// 239.339 us; speedup vs baseline: 1.6144x; 1.5922x over previous
//
#include <hip/hip_runtime.h>
#include <stdint.h>

typedef __attribute__((ext_vector_type(8))) short bf16x8;
typedef __attribute__((ext_vector_type(16))) float f32x16;

#define CH_STRIDE 65536  // T*W*H = 16*64*64

__device__ __forceinline__ uint16_t f2bf(float f) {
  uint32_t u = __builtin_bit_cast(uint32_t, f);
  u = (u + 0x7FFFu + ((u >> 16) & 1u)) >> 16;
  return (uint16_t)u;
}

__device__ __forceinline__ float bf2f(uint32_t b) {
  return __builtin_bit_cast(float, b << 16);
}

#define MFMA32(a, b, c) __builtin_amdgcn_mfma_f32_32x32x16_bf16(a, b, c, 0, 0, 0)

// ---------------------------------------------------------------------------
// x tile staging: rows w0-1..w0+4 (6), cols -1..64 (66), 64 ch as 8 octets.
// LDS layout: [r6][oct][col] of 16B frags (8 bf16 ch). All accesses to this
// layout (stage writes, B-frag reads, residual reads) are col-sequential ->
// conflict-free, no swizzle needed.
// ---------------------------------------------------------------------------
__device__ __forceinline__ void stage_x(uint8_t* ldsx, const float* xs, int w0, int tid) {
  for (int i = tid; i < 6 * 8 * 66; i += 512) {
    int roc = i / 66;          // r6*8 + oct
    int col = i - roc * 66;
    int r6  = roc >> 3;
    int oct = roc & 7;
    int w = w0 - 1 + r6;
    int h = col - 1;
    bf16x8 pk;
    if ((unsigned)w < 64u && (unsigned)h < 64u) {
      const float* p = xs + (size_t)(oct * 8) * CH_STRIDE + w * 64 + h;
      #pragma unroll
      for (int j = 0; j < 8; ++j) pk[j] = (short)f2bf(p[(size_t)j * CH_STRIDE]);
    } else {
      #pragma unroll
      for (int j = 0; j < 8; ++j) pk[j] = 0;
    }
    *(bf16x8*)(ldsx + (uint32_t)i * 16u) = pk;
  }
}

// B-frag (x side) for 32x32x16: lane l -> col = n0 + (l&31), k-octet oct.
__device__ __forceinline__ bf16x8 read_bx(const uint8_t* ldsx, int r6, int oct, int col) {
  return *(const bf16x8*)(ldsx + (uint32_t)((r6 * 8 + oct) * 66 + col) * 16u);
}

// ---------------------------------------------------------------------------
// A (weight) staging for one tap: nrow rows x 64 ch -> LDS [oct][row] 16B
// frags, byte ^= oct<<4 so stage writes (oct fast across lanes) and frag
// reads (row fast) are both bank-conflict-free.
// ---------------------------------------------------------------------------
__device__ __forceinline__ void stage_a(uint8_t* ldsa, const uint16_t* wtab,
                                        int tap, int tid, int nrow) {
  for (int i = tid; i < nrow * 8; i += 512) {
    int oct = i & 7;
    int row = i >> 3;
    bf16x8 frag = *(const bf16x8*)(wtab + (size_t)row * 576 + tap * 64 + oct * 8);
    uint32_t byte = ((uint32_t)(oct * nrow + row) * 16u) ^ ((uint32_t)oct << 4);
    *(bf16x8*)(ldsa + byte) = frag;
  }
}

__device__ __forceinline__ bf16x8 read_a(const uint8_t* ldsa, int nrow, int oct, int row) {
  uint32_t byte = ((uint32_t)(oct * nrow + row) * 16u) ^ ((uint32_t)oct << 4);
  return *(const bf16x8*)(ldsa + byte);
}

// ---------------------------------------------------------------------------
// Pre-kernel: weights fp32 [o][i][tap] -> bf16 [conv][m][K], K = tap*64 + ch
// ---------------------------------------------------------------------------
__global__ void prep_weights(const float* __restrict__ wq, const float* __restrict__ wk,
                             const float* __restrict__ wv, uint16_t* __restrict__ wout) {
  int i = blockIdx.x * 256 + threadIdx.x;
  if (i >= 3 * 64 * 576) return;
  int conv = i / 36864;
  int rem  = i - conv * 36864;
  int m    = rem / 576;
  int kk   = rem - m * 576;
  int tap  = kk >> 6;
  int ch   = kk & 63;
  const float* src = (conv == 0) ? wq : (conv == 1) ? wk : wv;
  wout[i] = f2bf(src[(m * 64 + ch) * 9 + tap]);
}

// ---------------------------------------------------------------------------
// Kernel 1: k,v conv (M=128) on a 4-row x 64-col tile; 8 waves (2 mg x 4 ng).
// Weights staged per tap in LDS. 32x32x16 MFMA. Wave mg owns k-ch and v-ch
// [mg*32, mg*32+32) so the k*v product is wave-local.
// ---------------------------------------------------------------------------
__global__ __launch_bounds__(512, 4) void kv_s_kernel(
    const float* __restrict__ x, const uint16_t* __restrict__ wkv,
    const float* __restrict__ bk, const float* __restrict__ bv,
    float* __restrict__ s_out) {
  extern __shared__ uint8_t lds[];
  uint8_t* ldsx = lds;          // 50688 B
  uint8_t* ldsa = lds + 50688;  // 16384 B
  int tid = threadIdx.x;
  int l   = tid & 63;
  int wid = tid >> 6;
  int bid = blockIdx.x;
  int rg    = bid & 15;
  int slice = bid >> 4;
  int b = slice >> 4, t = slice & 15;
  int w0 = rg * 4;
  const float* xs = x + ((size_t)b * 64 * 16 + t) * 4096;
  stage_x(ldsx, xs, w0, tid);

  int mg = wid >> 2;  // channel half
  int ng = wid & 3;   // position row
  int lm = l & 31, lh = l >> 5;

  f32x16 accK[2], accV[2];
  #pragma unroll
  for (int nt = 0; nt < 2; ++nt) {
    #pragma unroll
    for (int r = 0; r < 16; ++r) { accK[nt][r] = 0.f; accV[nt][r] = 0.f; }
  }

  for (int tap = 0; tap < 9; ++tap) {
    int dy = tap / 3, dx = tap % 3;
    __syncthreads();                    // ldsx ready (tap 0) / ldsa drained
    stage_a(ldsa, wkv, tap, tid, 128);  // k rows 0-63, v rows 64-127
    __syncthreads();
    #pragma unroll
    for (int s = 0; s < 4; ++s) {
      int oct = s * 2 + lh;
      bf16x8 aK = read_a(ldsa, 128, oct, mg * 32 + lm);
      bf16x8 aV = read_a(ldsa, 128, oct, 64 + mg * 32 + lm);
      #pragma unroll
      for (int nt = 0; nt < 2; ++nt) {
        bf16x8 bb = read_bx(ldsx, ng + dy, oct, nt * 32 + lm + dx);
        accK[nt] = MFMA32(aK, bb, accK[nt]);
        accV[nt] = MFMA32(aV, bb, accV[nt]);
      }
    }
  }

  // epilogue: s[b,c,t] += sum_pos (k+bk)*(v+bv)
  // C/D map: col = lane&31 (position), row_local = (r&3) + 8*(r>>2) + 4*lh
  int cbase = mg * 32;
  float part[16];
  #pragma unroll
  for (int r = 0; r < 16; ++r) {
    int cl = (r & 3) + 8 * (r >> 2) + 4 * lh;
    int c  = cbase + cl;
    float bkc = bk[c], bvc = bv[c];
    float p = 0.f;
    #pragma unroll
    for (int nt = 0; nt < 2; ++nt)
      p += (accK[nt][r] + bkc) * (accV[nt][r] + bvc);
    #pragma unroll
    for (int m = 1; m < 32; m <<= 1) p += __shfl_xor(p, m, 64);
    part[r] = p;
  }
  if (lm == 0) {
    float* sb = s_out + (b * 16 + t) * 64;
    #pragma unroll
    for (int r = 0; r < 16; ++r) {
      int cl = (r & 3) + 8 * (r >> 2) + 4 * lh;
      atomicAdd(sb + cbase + cl, part[r]);
    }
  }
}

// ---------------------------------------------------------------------------
// Kernel 2: q conv (M=64) + out = gamma*q*s + x; 8 waves (2 mg x 4 ng).
// Residual x read from the staged bf16 LDS tile.
// ---------------------------------------------------------------------------
__global__ __launch_bounds__(512, 4) void q_out_kernel(
    const float* __restrict__ x, const uint16_t* __restrict__ wq,
    const float* __restrict__ bq, const float* __restrict__ s_in,
    const float* __restrict__ gamma, float* __restrict__ out) {
  extern __shared__ uint8_t lds[];
  uint8_t* ldsx = lds;          // 50688 B
  uint8_t* ldsa = lds + 50688;  // 8192 B
  int tid = threadIdx.x;
  int l   = tid & 63;
  int wid = tid >> 6;
  int bid = blockIdx.x;
  int rg    = bid & 15;
  int slice = bid >> 4;
  int b = slice >> 4, t = slice & 15;
  int w0 = rg * 4;
  const float* xs = x + ((size_t)b * 64 * 16 + t) * 4096;
  stage_x(ldsx, xs, w0, tid);

  int mg = wid >> 2;  // channel half
  int ng = wid & 3;   // position row
  int lm = l & 31, lh = l >> 5;

  f32x16 acc[2];
  #pragma unroll
  for (int nt = 0; nt < 2; ++nt)
    #pragma unroll
    for (int r = 0; r < 16; ++r) acc[nt][r] = 0.f;

  for (int tap = 0; tap < 9; ++tap) {
    int dy = tap / 3, dx = tap % 3;
    __syncthreads();
    stage_a(ldsa, wq, tap, tid, 64);
    __syncthreads();
    #pragma unroll
    for (int s = 0; s < 4; ++s) {
      int oct = s * 2 + lh;
      bf16x8 aQ = read_a(ldsa, 64, oct, mg * 32 + lm);
      #pragma unroll
      for (int nt = 0; nt < 2; ++nt) {
        bf16x8 bb = read_bx(ldsx, ng + dy, oct, nt * 32 + lm + dx);
        acc[nt] = MFMA32(aQ, bb, acc[nt]);
      }
    }
  }

  float g = gamma[0];
  const float* sb = s_in + (b * 16 + t) * 64;
  #pragma unroll
  for (int nt = 0; nt < 2; ++nt) {
    int pcol = nt * 32 + lm;
    int w = w0 + ng;
    int h = pcol;
    #pragma unroll
    for (int r = 0; r < 16; ++r) {
      int cl = (r & 3) + 8 * (r >> 2) + 4 * lh;
      int c  = mg * 32 + cl;
      float qv = acc[nt][r] + bq[c];
      // residual x from staged tile: (r6 = ng+1, oct = c>>3, col = pcol+1, elem c&7)
      uint32_t xb = (uint32_t)(((ng + 1) * 8 + (c >> 3)) * 66 + (pcol + 1)) * 16u
                  + (uint32_t)(c & 7) * 2u;
      float xv = bf2f(*(const uint16_t*)(ldsx + xb));
      size_t idx = ((size_t)(b * 64 + c) * 16 + t) * 4096 + (size_t)w * 64 + h;
      out[idx] = g * qv * sb[c] + xv;
    }
  }
}

extern "C" void kernel_launch(void* const* d_in, const int* in_sizes, int n_in,
                              void* d_out, int out_size, void* d_ws, size_t ws_size,
                              hipStream_t stream) {
  const float* x   = (const float*)d_in[0];
  const float* wq  = (const float*)d_in[1];
  const float* wk  = (const float*)d_in[2];
  const float* wv  = (const float*)d_in[3];
  const float* bq  = (const float*)d_in[4];
  const float* bk  = (const float*)d_in[5];
  const float* bv  = (const float*)d_in[6];
  const float* gam = (const float*)d_in[7];

  uint16_t* wbf = (uint16_t*)d_ws;                           // 3 * 64*576 bf16
  float* sbuf   = (float*)((uint8_t*)d_ws + 3 * 36864 * 2);  // 8192 floats

  hipMemsetAsync(sbuf, 0, 8 * 16 * 64 * sizeof(float), stream);
  prep_weights<<<(3 * 64 * 576 + 255) / 256, 256, 0, stream>>>(wq, wk, wv, wbf);
  kv_s_kernel<<<2048, 512, 50688 + 16384, stream>>>(x, wbf + 36864, bk, bv, sbuf);
  q_out_kernel<<<2048, 512, 50688 + 8192, stream>>>(x, wbf, bq, sbuf, gam, (float*)d_out);
}

// Round 6
// 232.135 us; speedup vs baseline: 1.6645x; 1.0310x over previous
//
#include <hip/hip_runtime.h>
#include <stdint.h>

typedef __attribute__((ext_vector_type(8))) short bf16x8;
typedef __attribute__((ext_vector_type(16))) float f32x16;

#define CH_STRIDE 65536  // T*W*H

__device__ __forceinline__ uint16_t f2bf(float f) {
  uint32_t u = __builtin_bit_cast(uint32_t, f);
  u = (u + 0x7FFFu + ((u >> 16) & 1u)) >> 16;
  return (uint16_t)u;
}
__device__ __forceinline__ float bf2f(uint32_t b) {
  return __builtin_bit_cast(float, b << 16);
}

#define MFMA32(a, b, c) __builtin_amdgcn_mfma_f32_32x32x16_bf16(a, b, c, 0, 0, 0)

// LDS map: x tile [row10][oct8][col66] 16B frags = 84480 B; weights after.
#define LDSX_BYTES 84480

__device__ __forceinline__ bf16x8 ldx(const uint8_t* lds, int row, int oct, int colidx) {
  return *(const bf16x8*)(lds + (uint32_t)((row * 8 + oct) * 66 + colidx) * 16u);
}
// weights LDS: [tapc][oct][rowloc64] 16B frags (linear i = tapc*512+oct*64+rowloc)
__device__ __forceinline__ bf16x8 ldw(const uint8_t* ldsw, int tapc, int oct, int rowloc) {
  return *(const bf16x8*)(ldsw + (uint32_t)((tapc * 8 + oct) * 64 + rowloc) * 16u);
}

// Stage x: rows w0-1..w0+8 (10), interior cols 0..63 at colidx 1..64, halo
// colidx 0/65 = image boundary = zeros. 5120 interior frags = 10/thread.
__device__ __forceinline__ void stage_x_block(uint8_t* lds, const float* xs, int w0, int tid) {
  if (tid < 160) {
    int row = tid >> 4, rem = tid & 15;
    int oct = rem & 7, side = rem >> 3;
    bf16x8 z = {};
    *(bf16x8*)(lds + (uint32_t)((row * 8 + oct) * 66 + side * 65) * 16u) = z;
  }
  #pragma unroll
  for (int r = 0; r < 10; ++r) {
    int i = tid + r * 512;
    int col = i & 63, oct = (i >> 6) & 7, row = i >> 9;
    int w = w0 - 1 + row;
    bf16x8 pk = {};
    if ((unsigned)w < 64u) {
      const float* p = xs + (size_t)(oct * 8) * CH_STRIDE + w * 64 + col;
      #pragma unroll
      for (int j = 0; j < 8; ++j) pk[j] = (short)f2bf(p[(size_t)j * CH_STRIDE]);
    }
    *(bf16x8*)(lds + (uint32_t)((row * 8 + oct) * 66 + col + 1) * 16u) = pk;
  }
}

// Weight chunk load: NT taps, 64 rowlocs. kv: rowloc 0-31 = k rows cg*32+,
// rowloc 32-63 = v rows 64+cg*32+. q: rowloc = row, cg=0, voff=0.
template <int NT>
__device__ __forceinline__ void ldw_g(bf16x8* wreg, const uint16_t* wtab,
                                      int cg, int tap0, int tid) {
  #pragma unroll
  for (int r = 0; r < NT; ++r) {
    int i = tid + r * 512;
    int rowloc = i & 63, oct = (i >> 6) & 7, tapc = i >> 9;
    int grow = (rowloc & 31) + cg * 32 + (rowloc >> 5) * 64;
    wreg[r] = *(const bf16x8*)(wtab + (size_t)grow * 576 + (tap0 + tapc) * 64 + oct * 8);
  }
}
template <int NT>
__device__ __forceinline__ void ldw_g_q(bf16x8* wreg, const uint16_t* wtab,
                                        int tap0, int tid) {
  #pragma unroll
  for (int r = 0; r < NT; ++r) {
    int i = tid + r * 512;
    int rowloc = i & 63, oct = (i >> 6) & 7, tapc = i >> 9;
    wreg[r] = *(const bf16x8*)(wtab + (size_t)rowloc * 576 + (tap0 + tapc) * 64 + oct * 8);
  }
}
template <int NT>
__device__ __forceinline__ void stw_lds(uint8_t* ldsw, const bf16x8* wreg, int tid) {
  #pragma unroll
  for (int r = 0; r < NT; ++r)
    *(bf16x8*)(ldsw + (uint32_t)(tid + r * 512) * 16u) = wreg[r];
}

// ---------------------------------------------------------------------------
__global__ void prep_weights(const float* __restrict__ wq, const float* __restrict__ wk,
                             const float* __restrict__ wv, uint16_t* __restrict__ wout) {
  int i = blockIdx.x * 256 + threadIdx.x;
  if (i >= 3 * 64 * 576) return;
  int conv = i / 36864;
  int rem  = i - conv * 36864;
  int m    = rem / 576;
  int kk   = rem - m * 576;
  int tap  = kk >> 6;
  int ch   = kk & 63;
  const float* src = (conv == 0) ? wq : (conv == 1) ? wk : wv;
  wout[i] = f2bf(src[(m * 64 + ch) * 9 + tap]);
}

// ---------------------------------------------------------------------------
// KV kernel: block = (slice, rg of 8 rows). x staged once; weights in 4
// phases (cg 0/1 x tap-chunks 5/4) with reg-prefetch. Wave wid = output row.
// ---------------------------------------------------------------------------
template <int NT, int TAP0>
__device__ __forceinline__ void compute_kv(const uint8_t* lds, const uint8_t* ldsw,
                                           f32x16* accK, f32x16* accV,
                                           int wid, int lm, int lh) {
  #pragma unroll
  for (int tapc = 0; tapc < NT; ++tapc) {
    int tap = TAP0 + tapc;
    int dy = tap / 3, dx = tap % 3;
    #pragma unroll
    for (int s = 0; s < 4; ++s) {
      int oct = s * 2 + lh;
      bf16x8 aK = ldw(ldsw, tapc, oct, lm);
      bf16x8 aV = ldw(ldsw, tapc, oct, 32 + lm);
      bf16x8 b0 = ldx(lds, wid + dy, oct, lm + dx);
      bf16x8 b1 = ldx(lds, wid + dy, oct, 32 + lm + dx);
      accK[0] = MFMA32(aK, b0, accK[0]);
      accK[1] = MFMA32(aK, b1, accK[1]);
      accV[0] = MFMA32(aV, b0, accV[0]);
      accV[1] = MFMA32(aV, b1, accV[1]);
    }
  }
}

__device__ __forceinline__ void epi_kv(f32x16* accK, f32x16* accV,
                                       const float* bk, const float* bv,
                                       float* s_out, int b, int t, int cg,
                                       int l, int lh) {
  float* sb = s_out + (b * 16 + t) * 64;
  #pragma unroll
  for (int r = 0; r < 16; ++r) {
    int cl = (r & 3) + 8 * (r >> 2) + 4 * lh;
    int c  = cg * 32 + cl;
    float bkc = bk[c], bvc = bv[c];
    float p = (accK[0][r] + bkc) * (accV[0][r] + bvc)
            + (accK[1][r] + bkc) * (accV[1][r] + bvc);
    #pragma unroll
    for (int m = 1; m < 32; m <<= 1) p += __shfl_xor(p, m, 64);
    if ((l & 31) == 0) atomicAdd(sb + c, p);
  }
}

__global__ __launch_bounds__(512, 2) void kv_s_kernel(
    const float* __restrict__ x, const uint16_t* __restrict__ wkv,
    const float* __restrict__ bk, const float* __restrict__ bv,
    float* __restrict__ s_out) {
  extern __shared__ uint8_t lds[];
  uint8_t* ldsw = lds + LDSX_BYTES;
  int tid = threadIdx.x;
  int l = tid & 63, wid = tid >> 6;
  int bid = blockIdx.x;
  int rg = bid & 7, slice = bid >> 3;
  int b = slice >> 4, t = slice & 15;
  int w0 = rg * 8;
  const float* xs = x + ((size_t)b * 64 * 16 + t) * 4096;
  int lm = l & 31, lh = l >> 5;

  stage_x_block(lds, xs, w0, tid);
  bf16x8 wreg[5];
  ldw_g<5>(wreg, wkv, 0, 0, tid);   // phase 0: cg0 taps 0-4
  stw_lds<5>(ldsw, wreg, tid);
  __syncthreads();

  f32x16 accK[2], accV[2];
  #pragma unroll
  for (int nt = 0; nt < 2; ++nt)
    #pragma unroll
    for (int r = 0; r < 16; ++r) { accK[nt][r] = 0.f; accV[nt][r] = 0.f; }

  // phase 0 compute; prefetch phase 1 (cg0 taps 5-8)
  ldw_g<4>(wreg, wkv, 0, 5, tid);
  compute_kv<5, 0>(lds, ldsw, accK, accV, wid, lm, lh);
  __syncthreads();
  stw_lds<4>(ldsw, wreg, tid);
  __syncthreads();

  // phase 1 compute; prefetch phase 2 (cg1 taps 0-4)
  ldw_g<5>(wreg, wkv, 1, 0, tid);
  compute_kv<4, 5>(lds, ldsw, accK, accV, wid, lm, lh);
  epi_kv(accK, accV, bk, bv, s_out, b, t, 0, l, lh);
  #pragma unroll
  for (int nt = 0; nt < 2; ++nt)
    #pragma unroll
    for (int r = 0; r < 16; ++r) { accK[nt][r] = 0.f; accV[nt][r] = 0.f; }
  __syncthreads();
  stw_lds<5>(ldsw, wreg, tid);
  __syncthreads();

  // phase 2 compute; prefetch phase 3 (cg1 taps 5-8)
  ldw_g<4>(wreg, wkv, 1, 5, tid);
  compute_kv<5, 0>(lds, ldsw, accK, accV, wid, lm, lh);
  __syncthreads();
  stw_lds<4>(ldsw, wreg, tid);
  __syncthreads();

  // phase 3 compute
  compute_kv<4, 5>(lds, ldsw, accK, accV, wid, lm, lh);
  epi_kv(accK, accV, bk, bv, s_out, b, t, 1, l, lh);
}

// ---------------------------------------------------------------------------
// Q kernel: M=64 q rows, same x tile; 2 weight phases; fused epilogue.
// ---------------------------------------------------------------------------
template <int NT, int TAP0>
__device__ __forceinline__ void compute_q(const uint8_t* lds, const uint8_t* ldsw,
                                          f32x16 acc[2][2], int wid, int lm, int lh) {
  #pragma unroll
  for (int tapc = 0; tapc < NT; ++tapc) {
    int tap = TAP0 + tapc;
    int dy = tap / 3, dx = tap % 3;
    #pragma unroll
    for (int s = 0; s < 4; ++s) {
      int oct = s * 2 + lh;
      bf16x8 a0 = ldw(ldsw, tapc, oct, lm);
      bf16x8 a1 = ldw(ldsw, tapc, oct, 32 + lm);
      bf16x8 b0 = ldx(lds, wid + dy, oct, lm + dx);
      bf16x8 b1 = ldx(lds, wid + dy, oct, 32 + lm + dx);
      acc[0][0] = MFMA32(a0, b0, acc[0][0]);
      acc[0][1] = MFMA32(a0, b1, acc[0][1]);
      acc[1][0] = MFMA32(a1, b0, acc[1][0]);
      acc[1][1] = MFMA32(a1, b1, acc[1][1]);
    }
  }
}

__global__ __launch_bounds__(512, 2) void q_out_kernel(
    const float* __restrict__ x, const uint16_t* __restrict__ wq,
    const float* __restrict__ bq, const float* __restrict__ s_in,
    const float* __restrict__ gamma, float* __restrict__ out) {
  extern __shared__ uint8_t lds[];
  uint8_t* ldsw = lds + LDSX_BYTES;
  int tid = threadIdx.x;
  int l = tid & 63, wid = tid >> 6;
  int bid = blockIdx.x;
  int rg = bid & 7, slice = bid >> 3;
  int b = slice >> 4, t = slice & 15;
  int w0 = rg * 8;
  const float* xs = x + ((size_t)b * 64 * 16 + t) * 4096;
  int lm = l & 31, lh = l >> 5;

  stage_x_block(lds, xs, w0, tid);
  bf16x8 wreg[5];
  ldw_g_q<5>(wreg, wq, 0, tid);
  stw_lds<5>(ldsw, wreg, tid);
  __syncthreads();

  f32x16 acc[2][2];
  #pragma unroll
  for (int mt = 0; mt < 2; ++mt)
    #pragma unroll
    for (int nt = 0; nt < 2; ++nt)
      #pragma unroll
      for (int r = 0; r < 16; ++r) acc[mt][nt][r] = 0.f;

  ldw_g_q<4>(wreg, wq, 5, tid);
  compute_q<5, 0>(lds, ldsw, acc, wid, lm, lh);
  __syncthreads();
  stw_lds<4>(ldsw, wreg, tid);
  __syncthreads();
  compute_q<4, 5>(lds, ldsw, acc, wid, lm, lh);

  float g = gamma[0];
  const float* sb = s_in + (b * 16 + t) * 64;
  int w = w0 + wid;
  #pragma unroll
  for (int mt = 0; mt < 2; ++mt) {
    #pragma unroll
    for (int r = 0; r < 16; ++r) {
      int cl = (r & 3) + 8 * (r >> 2) + 4 * lh;
      int c  = mt * 32 + cl;
      float qb = bq[c], sc = sb[c];
      #pragma unroll
      for (int nt = 0; nt < 2; ++nt) {
        int h = nt * 32 + lm;
        uint32_t xb = (uint32_t)(((wid + 1) * 8 + (c >> 3)) * 66 + (h + 1)) * 16u
                    + (uint32_t)(c & 7) * 2u;
        float xv = bf2f(*(const uint16_t*)(lds + xb));
        size_t idx = ((size_t)(b * 64 + c) * 16 + t) * 4096 + (size_t)w * 64 + h;
        out[idx] = g * (acc[mt][nt][r] + qb) * sc + xv;
      }
    }
  }
}

extern "C" void kernel_launch(void* const* d_in, const int* in_sizes, int n_in,
                              void* d_out, int out_size, void* d_ws, size_t ws_size,
                              hipStream_t stream) {
  const float* x   = (const float*)d_in[0];
  const float* wq  = (const float*)d_in[1];
  const float* wk  = (const float*)d_in[2];
  const float* wv  = (const float*)d_in[3];
  const float* bq  = (const float*)d_in[4];
  const float* bk  = (const float*)d_in[5];
  const float* bv  = (const float*)d_in[6];
  const float* gam = (const float*)d_in[7];

  uint16_t* wbf = (uint16_t*)d_ws;                           // 3*64*576 bf16
  float* sbuf   = (float*)((uint8_t*)d_ws + 3 * 36864 * 2);  // 8192 floats

  hipMemsetAsync(sbuf, 0, 8 * 16 * 64 * sizeof(float), stream);
  prep_weights<<<(3 * 64 * 576 + 255) / 256, 256, 0, stream>>>(wq, wk, wv, wbf);
  size_t lds_kv = LDSX_BYTES + 5 * 512 * 16;  // 84480 + 40960 = 125440
  kv_s_kernel<<<1024, 512, lds_kv, stream>>>(x, wbf + 36864, bk, bv, sbuf);
  q_out_kernel<<<1024, 512, lds_kv, stream>>>(x, wbf, bq, sbuf, gam, (float*)d_out);
}

// Round 8
// 225.847 us; speedup vs baseline: 1.7108x; 1.0278x over previous
//
#include <hip/hip_runtime.h>
#include <stdint.h>

typedef __attribute__((ext_vector_type(8))) short bf16x8;
typedef __attribute__((ext_vector_type(16))) float f32x16;

#define CH_STRIDE 65536  // T*W*H

__device__ __forceinline__ uint16_t f2bf(float f) {
  uint32_t u = __builtin_bit_cast(uint32_t, f);
  u = (u + 0x7FFFu + ((u >> 16) & 1u)) >> 16;
  return (uint16_t)u;
}
__device__ __forceinline__ float bf2f(uint32_t b) {
  return __builtin_bit_cast(float, b << 16);
}

#define MFMA32(a, b, c) __builtin_amdgcn_mfma_f32_32x32x16_bf16(a, b, c, 0, 0, 0)
#define LGKM0 asm volatile("s_waitcnt lgkmcnt(0)" ::: "memory")
#define BAR __builtin_amdgcn_s_barrier()
#define SCHED0 __builtin_amdgcn_sched_barrier(0)

#define LDSX_BYTES (6 * 8 * 66 * 16)  // 50688

// x tile: [r6][oct][col66] 16B frags; col-sequential reads -> conflict-free.
__device__ __forceinline__ bf16x8 ldx(const uint8_t* ldsx, int r6, int oct, int colidx) {
  return *(const bf16x8*)(ldsx + (uint32_t)((r6 * 8 + oct) * 66 + colidx) * 16u);
}

__device__ __forceinline__ void stage_x(uint8_t* ldsx, const float* xs, int w0, int tid) {
  for (int i = tid; i < 6 * 8 * 66; i += 256) {
    int roc = i / 66;
    int col = i - roc * 66;
    int r6 = roc >> 3, oct = roc & 7;
    int w = w0 - 1 + r6, h = col - 1;
    bf16x8 pk = {};
    if ((unsigned)w < 64u && (unsigned)h < 64u) {
      const float* p = xs + (size_t)(oct * 8) * CH_STRIDE + w * 64 + h;
      #pragma unroll
      for (int j = 0; j < 8; ++j) pk[j] = (short)f2bf(p[(size_t)j * CH_STRIDE]);
    }
    *(bf16x8*)(ldsx + (uint32_t)i * 16u) = pk;
  }
}

// kv weights per tap: [oct8][rowloc128] (rowloc 0-63 = k rows, 64-127 = v rows)
__device__ __forceinline__ bf16x8 ldw_kv(const uint8_t* ldsw, int oct, int rowloc) {
  return *(const bf16x8*)(ldsw + (uint32_t)(oct * 128 + rowloc) * 16u);
}
__device__ __forceinline__ void ldw_g_kv(bf16x8* r, const uint16_t* wkv, int tap, int tid) {
  #pragma unroll
  for (int k = 0; k < 4; ++k) {
    int j = tid + k * 256;
    int oct = j >> 7, rowloc = j & 127;
    r[k] = *(const bf16x8*)(wkv + (size_t)rowloc * 576 + tap * 64 + oct * 8);
  }
}
__device__ __forceinline__ void stw_kv(uint8_t* ldsw, const bf16x8* r, int tid) {
  #pragma unroll
  for (int k = 0; k < 4; ++k)
    *(bf16x8*)(ldsw + (uint32_t)(tid + k * 256) * 16u) = r[k];
}

// q weights per tap: [oct8][row64]
__device__ __forceinline__ bf16x8 ldw_q(const uint8_t* ldsw, int oct, int row) {
  return *(const bf16x8*)(ldsw + (uint32_t)(oct * 64 + row) * 16u);
}
__device__ __forceinline__ void ldw_g_q(bf16x8* r, const uint16_t* wq, int tap, int tid) {
  #pragma unroll
  for (int k = 0; k < 2; ++k) {
    int j = tid + k * 256;
    int oct = j >> 6, row = j & 63;
    r[k] = *(const bf16x8*)(wq + (size_t)row * 576 + tap * 64 + oct * 8);
  }
}
__device__ __forceinline__ void stw_q(uint8_t* ldsw, const bf16x8* r, int tid) {
  #pragma unroll
  for (int k = 0; k < 2; ++k)
    *(bf16x8*)(ldsw + (uint32_t)(tid + k * 256) * 16u) = r[k];
}

// ---------------------------------------------------------------------------
__global__ void prep_weights(const float* __restrict__ wq, const float* __restrict__ wk,
                             const float* __restrict__ wv, uint16_t* __restrict__ wout) {
  int i = blockIdx.x * 256 + threadIdx.x;
  if (i >= 3 * 64 * 576) return;
  int conv = i / 36864;
  int rem  = i - conv * 36864;
  int m    = rem / 576;
  int kk   = rem - m * 576;
  int tap  = kk >> 6;
  int ch   = kk & 63;
  const float* src = (conv == 0) ? wq : (conv == 1) ? wk : wv;
  wout[i] = f2bf(src[(m * 64 + ch) * 9 + tap]);
}

// ---------------------------------------------------------------------------
// KV kernel: 256 thr / 4 waves; wave = output row ng; 6 reads -> 8 MFMA.
// Per-tap raw-barrier pipeline: weight loads stay in flight across barriers.
// ---------------------------------------------------------------------------
__global__ __launch_bounds__(256, 2) void kv_s_kernel(
    const float* __restrict__ x, const uint16_t* __restrict__ wkv,
    const float* __restrict__ bk, const float* __restrict__ bv,
    float* __restrict__ s_out) {
  extern __shared__ uint8_t lds[];
  uint8_t* ldsx = lds;
  uint8_t* ldsw = lds + LDSX_BYTES;
  const int tid = threadIdx.x;
  const int l = tid & 63, ng = tid >> 6;
  int bid = (int)(blockIdx.x & 7) * 256 + (int)(blockIdx.x >> 3);  // XCD swizzle
  const int rg = bid & 15, slice = bid >> 4;
  const int b = slice >> 4, t = slice & 15;
  const int w0 = rg * 4;
  const float* xs = x + ((size_t)b * 1024 + t) * 4096;
  const int lm = l & 31, lh = l >> 5;

  stage_x(ldsx, xs, w0, tid);
  bf16x8 r[4];
  ldw_g_kv(r, wkv, 0, tid);
  stw_kv(ldsw, r, tid);        // compiler inserts vmcnt wait for r
  ldw_g_kv(r, wkv, 1, tid);    // tap1 in flight across the barrier
  SCHED0; LGKM0; BAR; SCHED0;

  f32x16 accK[2][2], accV[2][2];
  #pragma unroll
  for (int mt = 0; mt < 2; ++mt)
    #pragma unroll
    for (int nt = 0; nt < 2; ++nt)
      #pragma unroll
      for (int q = 0; q < 16; ++q) { accK[mt][nt][q] = 0.f; accV[mt][nt][q] = 0.f; }

  #pragma unroll
  for (int tap = 0; tap < 9; ++tap) {
    const int dy = tap / 3, dx = tap % 3;
    __builtin_amdgcn_s_setprio(1);
    #pragma unroll
    for (int s = 0; s < 4; ++s) {
      int oct = s * 2 + lh;
      bf16x8 aK0 = ldw_kv(ldsw, oct, lm);
      bf16x8 aK1 = ldw_kv(ldsw, oct, 32 + lm);
      bf16x8 aV0 = ldw_kv(ldsw, oct, 64 + lm);
      bf16x8 aV1 = ldw_kv(ldsw, oct, 96 + lm);
      bf16x8 b0  = ldx(ldsx, ng + dy, oct, lm + dx);
      bf16x8 b1  = ldx(ldsx, ng + dy, oct, 32 + lm + dx);
      accK[0][0] = MFMA32(aK0, b0, accK[0][0]);
      accK[0][1] = MFMA32(aK0, b1, accK[0][1]);
      accK[1][0] = MFMA32(aK1, b0, accK[1][0]);
      accK[1][1] = MFMA32(aK1, b1, accK[1][1]);
      accV[0][0] = MFMA32(aV0, b0, accV[0][0]);
      accV[0][1] = MFMA32(aV0, b1, accV[0][1]);
      accV[1][0] = MFMA32(aV1, b0, accV[1][0]);
      accV[1][1] = MFMA32(aV1, b1, accV[1][1]);
    }
    __builtin_amdgcn_s_setprio(0);
    if (tap < 8) {
      SCHED0; BAR;               // all waves done reading ldsw(tap)
      stw_kv(ldsw, r, tid);      // write tap+1
      if (tap < 7) ldw_g_kv(r, wkv, tap + 2, tid);  // stays in flight
      SCHED0; LGKM0; BAR; SCHED0;  // ds_writes visible; vmcnt NOT drained
    }
  }

  // epilogue: s[b,c,t] += sum over this wave's 64 positions of (k+bk)(v+bv)
  float* sb = s_out + (b * 16 + t) * 64;
  #pragma unroll
  for (int q = 0; q < 16; ++q) {
    int cl = (q & 3) + 8 * (q >> 2) + 4 * lh;
    #pragma unroll
    for (int mt = 0; mt < 2; ++mt) {
      int c = mt * 32 + cl;
      float bkc = bk[c], bvc = bv[c];
      float p = (accK[mt][0][q] + bkc) * (accV[mt][0][q] + bvc)
              + (accK[mt][1][q] + bkc) * (accV[mt][1][q] + bvc);
      #pragma unroll
      for (int m = 1; m < 32; m <<= 1) p += __shfl_xor(p, m, 64);
      if (lm == 0) atomicAdd(sb + c, p);
    }
  }
}

// ---------------------------------------------------------------------------
// Q kernel: 256 thr / 4 waves; wave = row ng, all 64 q-ch; fused epilogue.
// ---------------------------------------------------------------------------
__global__ __launch_bounds__(256, 2) void q_out_kernel(
    const float* __restrict__ x, const uint16_t* __restrict__ wq,
    const float* __restrict__ bq, const float* __restrict__ s_in,
    const float* __restrict__ gamma, float* __restrict__ out) {
  extern __shared__ uint8_t lds[];
  uint8_t* ldsx = lds;
  uint8_t* ldsw = lds + LDSX_BYTES;
  const int tid = threadIdx.x;
  const int l = tid & 63, ng = tid >> 6;
  int bid = (int)(blockIdx.x & 7) * 256 + (int)(blockIdx.x >> 3);  // XCD swizzle
  const int rg = bid & 15, slice = bid >> 4;
  const int b = slice >> 4, t = slice & 15;
  const int w0 = rg * 4;
  const float* xs = x + ((size_t)b * 1024 + t) * 4096;
  const int lm = l & 31, lh = l >> 5;

  stage_x(ldsx, xs, w0, tid);
  bf16x8 r[2];
  ldw_g_q(r, wq, 0, tid);
  stw_q(ldsw, r, tid);
  ldw_g_q(r, wq, 1, tid);
  SCHED0; LGKM0; BAR; SCHED0;

  f32x16 acc[2][2];
  #pragma unroll
  for (int mt = 0; mt < 2; ++mt)
    #pragma unroll
    for (int nt = 0; nt < 2; ++nt)
      #pragma unroll
      for (int q = 0; q < 16; ++q) acc[mt][nt][q] = 0.f;

  #pragma unroll
  for (int tap = 0; tap < 9; ++tap) {
    const int dy = tap / 3, dx = tap % 3;
    __builtin_amdgcn_s_setprio(1);
    #pragma unroll
    for (int s = 0; s < 4; ++s) {
      int oct = s * 2 + lh;
      bf16x8 a0 = ldw_q(ldsw, oct, lm);
      bf16x8 a1 = ldw_q(ldsw, oct, 32 + lm);
      bf16x8 b0 = ldx(ldsx, ng + dy, oct, lm + dx);
      bf16x8 b1 = ldx(ldsx, ng + dy, oct, 32 + lm + dx);
      acc[0][0] = MFMA32(a0, b0, acc[0][0]);
      acc[0][1] = MFMA32(a0, b1, acc[0][1]);
      acc[1][0] = MFMA32(a1, b0, acc[1][0]);
      acc[1][1] = MFMA32(a1, b1, acc[1][1]);
    }
    __builtin_amdgcn_s_setprio(0);
    if (tap < 8) {
      SCHED0; BAR;
      stw_q(ldsw, r, tid);
      if (tap < 7) ldw_g_q(r, wq, tap + 2, tid);
      SCHED0; LGKM0; BAR; SCHED0;
    }
  }

  float g = gamma[0];
  const float* sb = s_in + (b * 16 + t) * 64;
  int w = w0 + ng;
  #pragma unroll
  for (int mt = 0; mt < 2; ++mt) {
    #pragma unroll
    for (int q = 0; q < 16; ++q) {
      int cl = (q & 3) + 8 * (q >> 2) + 4 * lh;
      int c  = mt * 32 + cl;
      float qb = bq[c], sc = sb[c];
      #pragma unroll
      for (int nt = 0; nt < 2; ++nt) {
        int h = nt * 32 + lm;
        uint32_t xb = (uint32_t)(((ng + 1) * 8 + (c >> 3)) * 66 + (h + 1)) * 16u
                    + (uint32_t)(c & 7) * 2u;
        float xv = bf2f(*(const uint16_t*)(ldsx + xb));
        size_t idx = ((size_t)(b * 64 + c) * 16 + t) * 4096 + (size_t)w * 64 + h;
        out[idx] = g * (acc[mt][nt][q] + qb) * sc + xv;
      }
    }
  }
}

extern "C" void kernel_launch(void* const* d_in, const int* in_sizes, int n_in,
                              void* d_out, int out_size, void* d_ws, size_t ws_size,
                              hipStream_t stream) {
  const float* x   = (const float*)d_in[0];
  const float* wq  = (const float*)d_in[1];
  const float* wk  = (const float*)d_in[2];
  const float* wv  = (const float*)d_in[3];
  const float* bq  = (const float*)d_in[4];
  const float* bk  = (const float*)d_in[5];
  const float* bv  = (const float*)d_in[6];
  const float* gam = (const float*)d_in[7];

  uint16_t* wbf = (uint16_t*)d_ws;                           // 3*64*576 bf16
  float* sbuf   = (float*)((uint8_t*)d_ws + 3 * 36864 * 2);  // 8192 floats

  hipMemsetAsync(sbuf, 0, 8 * 16 * 64 * sizeof(float), stream);
  prep_weights<<<(3 * 64 * 576 + 255) / 256, 256, 0, stream>>>(wq, wk, wv, wbf);
  kv_s_kernel<<<2048, 256, LDSX_BYTES + 16384, stream>>>(x, wbf + 36864, bk, bv, sbuf);
  q_out_kernel<<<2048, 256, LDSX_BYTES + 8192, stream>>>(x, wbf, bq, sbuf, gam, (float*)d_out);
}

// Round 9
// 206.658 us; speedup vs baseline: 1.8697x; 1.0929x over previous
//
#include <hip/hip_runtime.h>
#include <hip/hip_bf16.h>
#include <stdint.h>

typedef __attribute__((ext_vector_type(8))) short bf16x8;
typedef __attribute__((ext_vector_type(4))) float f32x4v;
typedef __attribute__((ext_vector_type(16))) float f32x16;

#define CH_STRIDE 65536  // T*W*H

__device__ __forceinline__ uint16_t f2bf(float f) {
  uint32_t u = __builtin_bit_cast(uint32_t, f);
  u = (u + 0x7FFFu + ((u >> 16) & 1u)) >> 16;
  return (uint16_t)u;
}
__device__ __forceinline__ float bf2f(uint32_t b) {
  return __builtin_bit_cast(float, b << 16);
}
__device__ __forceinline__ uint16_t cvt_bf(float f) {
  return __builtin_bit_cast(uint16_t, __float2bfloat16(f));
}

#define MFMA32(a, b, c) __builtin_amdgcn_mfma_f32_32x32x16_bf16(a, b, c, 0, 0, 0)
#define LGKM0 asm volatile("s_waitcnt lgkmcnt(0)" ::: "memory")
#define BAR __builtin_amdgcn_s_barrier()
#define SCHED0 __builtin_amdgcn_sched_barrier(0)

#define LDSX_BYTES (6 * 8 * 66 * 16)  // 50688

// XOR swizzle (bits 7-9 -> bits 4-6, bijective): spreads 64B-stride lane
// patterns across 8 16B slots. Applied to ALL ldsx accesses.
__device__ __forceinline__ uint32_t swz(uint32_t b) {
  return b ^ (((b >> 7) & 7u) << 4);
}

// x tile: [r6][oct][col66] 16B frags (8 bf16 ch), swizzled.
__device__ __forceinline__ bf16x8 ldx(const uint8_t* ldsx, int r6, int oct, int ci) {
  return *(const bf16x8*)(ldsx + swz((uint32_t)((r6 * 8 + oct) * 66 + ci) * 16u));
}

// Stage x: 768 interior units (r6, oct, colgroup of 4) + 96 halo frags.
// Per unit: 8 dwordx4 fp32 loads -> 32 bf16 -> 4 ds_write_b128.
__device__ __forceinline__ void stage_x(uint8_t* ldsx, const float* xs, int w0, int tid) {
  if (tid < 96) {  // col halo (h=-1, h=64): image padding = zeros
    int r6 = tid >> 4, rem = tid & 15;
    int oct = rem >> 1, side = rem & 1;
    bf16x8 z = {};
    *(bf16x8*)(ldsx + swz((uint32_t)((r6 * 8 + oct) * 66 + side * 65) * 16u)) = z;
  }
  #pragma unroll
  for (int k = 0; k < 3; ++k) {
    int u = tid + k * 256;
    int r6 = u >> 7, oct = (u >> 4) & 7, g = u & 15;
    int w = w0 - 1 + r6;
    uint32_t base = (uint32_t)((r6 * 8 + oct) * 66 + 4 * g + 1) * 16u;
    if ((unsigned)w < 64u) {
      const float* p = xs + (size_t)(oct * 8) * CH_STRIDE + w * 64 + 4 * g;
      f32x4v v[8];
      #pragma unroll
      for (int j = 0; j < 8; ++j) v[j] = *(const f32x4v*)(p + (size_t)j * CH_STRIDE);
      #pragma unroll
      for (int c = 0; c < 4; ++c) {
        bf16x8 frag;
        #pragma unroll
        for (int q = 0; q < 4; ++q) {
          frag[2 * q]     = (short)cvt_bf(v[2 * q][c]);
          frag[2 * q + 1] = (short)cvt_bf(v[2 * q + 1][c]);
        }
        *(bf16x8*)(ldsx + swz(base + (uint32_t)c * 16u)) = frag;
      }
    } else {
      bf16x8 z = {};
      #pragma unroll
      for (int c = 0; c < 4; ++c)
        *(bf16x8*)(ldsx + swz(base + (uint32_t)c * 16u)) = z;
    }
  }
}

// kv weights: GLOBAL layout [tap][frag j=oct*128+rowloc] (tap-contiguous,
// 16KB/tap) -> coalesced loads. LDS layout = same frag order.
__device__ __forceinline__ bf16x8 ldw_kv(const uint8_t* ldsw, int oct, int rowloc) {
  return *(const bf16x8*)(ldsw + (uint32_t)(oct * 128 + rowloc) * 16u);
}
__device__ __forceinline__ void ldw_g_kv(bf16x8* r, const uint16_t* wkv, int tap, int tid) {
  #pragma unroll
  for (int k = 0; k < 4; ++k)
    r[k] = *(const bf16x8*)(wkv + ((size_t)tap * 1024 + tid + k * 256) * 8);
}
__device__ __forceinline__ void stw_kv(uint8_t* ldsw, const bf16x8* r, int tid) {
  #pragma unroll
  for (int k = 0; k < 4; ++k)
    *(bf16x8*)(ldsw + (uint32_t)(tid + k * 256) * 16u) = r[k];
}

// q weights: GLOBAL layout [tap][frag j=oct*64+row] (8KB/tap).
__device__ __forceinline__ bf16x8 ldw_q(const uint8_t* ldsw, int oct, int row) {
  return *(const bf16x8*)(ldsw + (uint32_t)(oct * 64 + row) * 16u);
}
__device__ __forceinline__ void ldw_g_q(bf16x8* r, const uint16_t* wq, int tap, int tid) {
  #pragma unroll
  for (int k = 0; k < 2; ++k)
    r[k] = *(const bf16x8*)(wq + ((size_t)tap * 512 + tid + k * 256) * 8);
}
__device__ __forceinline__ void stw_q(uint8_t* ldsw, const bf16x8* r, int tid) {
  #pragma unroll
  for (int k = 0; k < 2; ++k)
    *(bf16x8*)(ldsw + (uint32_t)(tid + k * 256) * 16u) = r[k];
}

// ---------------------------------------------------------------------------
// Pre-kernel: fp32 [o][i][tap] -> bf16 tap-contiguous tables.
// wout[0..36863]  = q:  [tap][oct][row][j]
// wout[36864..]   = kv: [tap][oct][rowloc][j] (rowloc<64 = k, else v)
// ---------------------------------------------------------------------------
__global__ void prep_weights(const float* __restrict__ wq, const float* __restrict__ wk,
                             const float* __restrict__ wv, uint16_t* __restrict__ wout) {
  int i = blockIdx.x * 256 + threadIdx.x;
  if (i >= 110592) return;
  if (i < 36864) {
    int tap = i >> 12, oct = (i >> 9) & 7, row = (i >> 3) & 63, j = i & 7;
    wout[i] = f2bf(wq[(row * 64 + oct * 8 + j) * 9 + tap]);
  } else {
    int m = i - 36864;
    int tap = m >> 13, oct = (m >> 10) & 7, rl = (m >> 3) & 127, j = m & 7;
    const float* src = (rl < 64) ? wk : wv;
    wout[i] = f2bf(src[((rl & 63) * 64 + oct * 8 + j) * 9 + tap]);
  }
}

// ---------------------------------------------------------------------------
// KV kernel: 256 thr / 4 waves; wave = output row ng; per-tap raw-barrier
// pipeline with register-prefetched (coalesced) weights.
// ---------------------------------------------------------------------------
__global__ __launch_bounds__(256, 2) void kv_s_kernel(
    const float* __restrict__ x, const uint16_t* __restrict__ wkv,
    const float* __restrict__ bk, const float* __restrict__ bv,
    float* __restrict__ s_out) {
  extern __shared__ uint8_t lds[];
  uint8_t* ldsx = lds;
  uint8_t* ldsw = lds + LDSX_BYTES;
  const int tid = threadIdx.x;
  const int l = tid & 63, ng = tid >> 6;
  int bid = (int)(blockIdx.x & 7) * 256 + (int)(blockIdx.x >> 3);  // XCD swizzle
  const int rg = bid & 15, slice = bid >> 4;
  const int b = slice >> 4, t = slice & 15;
  const int w0 = rg * 4;
  const float* xs = x + ((size_t)b * 1024 + t) * 4096;
  const int lm = l & 31, lh = l >> 5;

  stage_x(ldsx, xs, w0, tid);
  bf16x8 r[4];
  ldw_g_kv(r, wkv, 0, tid);
  stw_kv(ldsw, r, tid);
  ldw_g_kv(r, wkv, 1, tid);    // tap1 in flight across the barrier
  SCHED0; LGKM0; BAR; SCHED0;

  f32x16 accK[2][2], accV[2][2];
  #pragma unroll
  for (int mt = 0; mt < 2; ++mt)
    #pragma unroll
    for (int nt = 0; nt < 2; ++nt)
      #pragma unroll
      for (int q = 0; q < 16; ++q) { accK[mt][nt][q] = 0.f; accV[mt][nt][q] = 0.f; }

  #pragma unroll
  for (int tap = 0; tap < 9; ++tap) {
    const int dy = tap / 3, dx = tap % 3;
    __builtin_amdgcn_s_setprio(1);
    #pragma unroll
    for (int s = 0; s < 4; ++s) {
      int oct = s * 2 + lh;
      bf16x8 aK0 = ldw_kv(ldsw, oct, lm);
      bf16x8 aK1 = ldw_kv(ldsw, oct, 32 + lm);
      bf16x8 aV0 = ldw_kv(ldsw, oct, 64 + lm);
      bf16x8 aV1 = ldw_kv(ldsw, oct, 96 + lm);
      bf16x8 b0  = ldx(ldsx, ng + dy, oct, lm + dx);
      bf16x8 b1  = ldx(ldsx, ng + dy, oct, 32 + lm + dx);
      accK[0][0] = MFMA32(aK0, b0, accK[0][0]);
      accK[0][1] = MFMA32(aK0, b1, accK[0][1]);
      accK[1][0] = MFMA32(aK1, b0, accK[1][0]);
      accK[1][1] = MFMA32(aK1, b1, accK[1][1]);
      accV[0][0] = MFMA32(aV0, b0, accV[0][0]);
      accV[0][1] = MFMA32(aV0, b1, accV[0][1]);
      accV[1][0] = MFMA32(aV1, b0, accV[1][0]);
      accV[1][1] = MFMA32(aV1, b1, accV[1][1]);
    }
    __builtin_amdgcn_s_setprio(0);
    if (tap < 8) {
      SCHED0; BAR;               // all waves done reading ldsw(tap)
      stw_kv(ldsw, r, tid);      // write tap+1
      if (tap < 7) ldw_g_kv(r, wkv, tap + 2, tid);  // stays in flight
      SCHED0; LGKM0; BAR; SCHED0;
    }
  }

  float* sb = s_out + (b * 16 + t) * 64;
  #pragma unroll
  for (int q = 0; q < 16; ++q) {
    int cl = (q & 3) + 8 * (q >> 2) + 4 * lh;
    #pragma unroll
    for (int mt = 0; mt < 2; ++mt) {
      int c = mt * 32 + cl;
      float bkc = bk[c], bvc = bv[c];
      float p = (accK[mt][0][q] + bkc) * (accV[mt][0][q] + bvc)
              + (accK[mt][1][q] + bkc) * (accV[mt][1][q] + bvc);
      #pragma unroll
      for (int m = 1; m < 32; m <<= 1) p += __shfl_xor(p, m, 64);
      if (lm == 0) atomicAdd(sb + c, p);
    }
  }
}

// ---------------------------------------------------------------------------
// Q kernel: 256 thr / 4 waves; wave = row ng; fused epilogue (residual from
// staged bf16 LDS tile).
// ---------------------------------------------------------------------------
__global__ __launch_bounds__(256, 2) void q_out_kernel(
    const float* __restrict__ x, const uint16_t* __restrict__ wq,
    const float* __restrict__ bq, const float* __restrict__ s_in,
    const float* __restrict__ gamma, float* __restrict__ out) {
  extern __shared__ uint8_t lds[];
  uint8_t* ldsx = lds;
  uint8_t* ldsw = lds + LDSX_BYTES;
  const int tid = threadIdx.x;
  const int l = tid & 63, ng = tid >> 6;
  int bid = (int)(blockIdx.x & 7) * 256 + (int)(blockIdx.x >> 3);  // XCD swizzle
  const int rg = bid & 15, slice = bid >> 4;
  const int b = slice >> 4, t = slice & 15;
  const int w0 = rg * 4;
  const float* xs = x + ((size_t)b * 1024 + t) * 4096;
  const int lm = l & 31, lh = l >> 5;

  stage_x(ldsx, xs, w0, tid);
  bf16x8 r[2];
  ldw_g_q(r, wq, 0, tid);
  stw_q(ldsw, r, tid);
  ldw_g_q(r, wq, 1, tid);
  SCHED0; LGKM0; BAR; SCHED0;

  f32x16 acc[2][2];
  #pragma unroll
  for (int mt = 0; mt < 2; ++mt)
    #pragma unroll
    for (int nt = 0; nt < 2; ++nt)
      #pragma unroll
      for (int q = 0; q < 16; ++q) acc[mt][nt][q] = 0.f;

  #pragma unroll
  for (int tap = 0; tap < 9; ++tap) {
    const int dy = tap / 3, dx = tap % 3;
    __builtin_amdgcn_s_setprio(1);
    #pragma unroll
    for (int s = 0; s < 4; ++s) {
      int oct = s * 2 + lh;
      bf16x8 a0 = ldw_q(ldsw, oct, lm);
      bf16x8 a1 = ldw_q(ldsw, oct, 32 + lm);
      bf16x8 b0 = ldx(ldsx, ng + dy, oct, lm + dx);
      bf16x8 b1 = ldx(ldsx, ng + dy, oct, 32 + lm + dx);
      acc[0][0] = MFMA32(a0, b0, acc[0][0]);
      acc[0][1] = MFMA32(a0, b1, acc[0][1]);
      acc[1][0] = MFMA32(a1, b0, acc[1][0]);
      acc[1][1] = MFMA32(a1, b1, acc[1][1]);
    }
    __builtin_amdgcn_s_setprio(0);
    if (tap < 8) {
      SCHED0; BAR;
      stw_q(ldsw, r, tid);
      if (tap < 7) ldw_g_q(r, wq, tap + 2, tid);
      SCHED0; LGKM0; BAR; SCHED0;
    }
  }

  float g = gamma[0];
  const float* sb = s_in + (b * 16 + t) * 64;
  int w = w0 + ng;
  #pragma unroll
  for (int mt = 0; mt < 2; ++mt) {
    #pragma unroll
    for (int q = 0; q < 16; ++q) {
      int cl = (q & 3) + 8 * (q >> 2) + 4 * lh;
      int c  = mt * 32 + cl;
      float qb = bq[c], sc = sb[c];
      #pragma unroll
      for (int nt = 0; nt < 2; ++nt) {
        int h = nt * 32 + lm;
        uint32_t xb = (uint32_t)(((ng + 1) * 8 + (c >> 3)) * 66 + (h + 1)) * 16u
                    + (uint32_t)(c & 7) * 2u;
        float xv = bf2f(*(const uint16_t*)(ldsx + swz(xb)));
        size_t idx = ((size_t)(b * 64 + c) * 16 + t) * 4096 + (size_t)w * 64 + h;
        out[idx] = g * (acc[mt][nt][q] + qb) * sc + xv;
      }
    }
  }
}

extern "C" void kernel_launch(void* const* d_in, const int* in_sizes, int n_in,
                              void* d_out, int out_size, void* d_ws, size_t ws_size,
                              hipStream_t stream) {
  const float* x   = (const float*)d_in[0];
  const float* wq  = (const float*)d_in[1];
  const float* wk  = (const float*)d_in[2];
  const float* wv  = (const float*)d_in[3];
  const float* bq  = (const float*)d_in[4];
  const float* bk  = (const float*)d_in[5];
  const float* bv  = (const float*)d_in[6];
  const float* gam = (const float*)d_in[7];

  uint16_t* wbf = (uint16_t*)d_ws;                           // 110592 bf16
  float* sbuf   = (float*)((uint8_t*)d_ws + 3 * 36864 * 2);  // 8192 floats

  hipMemsetAsync(sbuf, 0, 8 * 16 * 64 * sizeof(float), stream);
  prep_weights<<<(110592 + 255) / 256, 256, 0, stream>>>(wq, wk, wv, wbf);
  kv_s_kernel<<<2048, 256, LDSX_BYTES + 16384, stream>>>(x, wbf + 36864, bk, bv, sbuf);
  q_out_kernel<<<2048, 256, LDSX_BYTES + 8192, stream>>>(x, wbf, bq, sbuf, gam, (float*)d_out);
}